// Round 2
// baseline (327.145 us; speedup 1.0000x reference)
//
#include <hip/hip_runtime.h>
#include <hip/hip_cooperative_groups.h>

namespace coopg = cooperative_groups;

#define EPS 1e-5f

typedef __bf16 bf16x8 __attribute__((ext_vector_type(8)));
typedef float f32x4 __attribute__((ext_vector_type(4)));

union BF8 { bf16x8 v; unsigned short u[8]; uint4 q; };

__device__ inline unsigned short f32_to_bf16(float f) {
    unsigned u = __builtin_bit_cast(unsigned, f);
    return (unsigned short)((u + 0x7FFFu + ((u >> 16) & 1u)) >> 16);
}
__device__ inline float relu6f(float x) { return fminf(fmaxf(x, 0.f), 6.f); }

// ================= single cooperative kernel =================
// Phase 1: x1 = u8-quant(relu6(bn1(feats @ W1)))   [96 rows/block, grid-stride]
// grid.sync()
// Phase 2: depthwise gather + bn2 + relu6 + project GEMM + bn3 + residual
//          [48 rows/tile, grid-stride, body identical to the proven k2]
// All weight prep (W1^T/W3^T bf16 frags, bn constants) folded per-block from
// L2-hot tables (W1: 24 KB, W3: 24 KB) -> no k0, no table workspace.
__global__ __launch_bounds__(192) void fused(
    const float* __restrict__ feats, const int* __restrict__ nbr,
    const float* __restrict__ W1, const float* __restrict__ W2,
    const float* __restrict__ W3,
    const float* __restrict__ g1, const float* __restrict__ b1,
    const float* __restrict__ m1, const float* __restrict__ v1,
    const float* __restrict__ g2, const float* __restrict__ b2,
    const float* __restrict__ m2, const float* __restrict__ v2,
    const float* __restrict__ g3, const float* __restrict__ b3,
    const float* __restrict__ m3, const float* __restrict__ v3,
    unsigned char* __restrict__ x1, float* __restrict__ out,
    int N, int nt1, int nt2)
{
    // overlapped LDS: phase1 {outB[96*52]u32 (19968) | bn1[384]f32 (1536)}
    //                 phase2 {x2L[48*200]u16 (19200) | offL[48*12]i32 (2304)}
    __shared__ __align__(16) char sh[21504];
    unsigned*       outB = (unsigned*)sh;
    float*          bn1  = (float*)(sh + 19968);
    unsigned short* x2L  = (unsigned short*)sh;
    int*            offL = (int*)(sh + 19200);

    const int tid  = threadIdx.x;
    const int lane = tid & 63, wave = tid >> 6;
    const int m = lane & 15, q = lane >> 4;

    // ---------- phase-1 prep: bn1 constants in LDS, W1^T frags in regs ----------
    {
        const float Q = 255.f / 6.f;
        int c = tid;                       // 192 threads == 192 channels
        float s = g1[c] * rsqrtf(v1[c] + EPS);
        bn1[c]       = s * Q;
        bn1[192 + c] = (b1[c] - m1[c] * s) * Q;
    }
    BF8 bf[12];                            // A-frag: A[outch=16t+m][k=q*8+j]
#pragma unroll
    for (int t = 0; t < 12; ++t)
#pragma unroll
        for (int j = 0; j < 8; ++j)
            bf[t].u[j] = f32_to_bf16(W1[(q * 8 + j) * 192 + 16 * t + m]);
    __syncthreads();

    // ---------- phase 1: grid-stride over 96-row tiles ----------
    for (int tb = blockIdx.x; tb < nt1; tb += gridDim.x) {
        const int rowbase = tb * 96;
#pragma unroll
        for (int p = 0; p < 2; ++p) {
            const int tile = wave * 2 + p;           // 0..5
            const int row = rowbase + tile * 16 + m;
            float4 f0 = {0.f,0.f,0.f,0.f}, f1 = {0.f,0.f,0.f,0.f};
            if (row < N) {
                f0 = *(const float4*)(feats + (size_t)row * 32 + q * 8);
                f1 = *(const float4*)(feats + (size_t)row * 32 + q * 8 + 4);
            }
            BF8 af;                                  // B-frag: B[k=q*8+j][pt=m]
            af.u[0] = f32_to_bf16(f0.x); af.u[1] = f32_to_bf16(f0.y);
            af.u[2] = f32_to_bf16(f0.z); af.u[3] = f32_to_bf16(f0.w);
            af.u[4] = f32_to_bf16(f1.x); af.u[5] = f32_to_bf16(f1.y);
            af.u[6] = f32_to_bf16(f1.z); af.u[7] = f32_to_bf16(f1.w);

            f32x4 acc[12];
#pragma unroll
            for (int t = 0; t < 12; ++t) {
                f32x4 z = {0.f, 0.f, 0.f, 0.f};
                acc[t] = __builtin_amdgcn_mfma_f32_16x16x32_bf16(bf[t].v, af.v, z, 0, 0, 0);
            }

            // lane owns channels {16t+4q..+3} of point (tile*16+m): pack 4 u8 -> b32
            const int rl = tile * 16 + m;
#pragma unroll
            for (int t = 0; t < 12; ++t) {
                float4 sv = *(const float4*)(bn1 + 16 * t + 4 * q);
                float4 bv = *(const float4*)(bn1 + 192 + 16 * t + 4 * q);
                float y0 = fminf(fmaxf(fmaf(acc[t][0], sv.x, bv.x), 0.f), 255.f);
                float y1 = fminf(fmaxf(fmaf(acc[t][1], sv.y, bv.y), 0.f), 255.f);
                float y2 = fminf(fmaxf(fmaf(acc[t][2], sv.z, bv.z), 0.f), 255.f);
                float y3 = fminf(fmaxf(fmaf(acc[t][3], sv.w, bv.w), 0.f), 255.f);
                unsigned d = (unsigned)(y0 + 0.5f)
                           | ((unsigned)(y1 + 0.5f) << 8)
                           | ((unsigned)(y2 + 0.5f) << 16)
                           | ((unsigned)(y3 + 0.5f) << 24);
                outB[rl * 52 + 4 * t + q] = d;
            }
        }
        __syncthreads();
        // readout: 96 rows x 12 uint4-chunks = 1152, coalesced global stores
#pragma unroll
        for (int j = 0; j < 6; ++j) {
            int i = j * 192 + tid;
            int r = i / 12, c = i % 12;
            int gr = rowbase + r;
            if (gr < N)
                *(uint4*)(x1 + (size_t)gr * 192 + c * 16) = *(const uint4*)(&outB[r * 52 + c * 4]);
        }
        __syncthreads();                   // outB reused next tile
    }

    coopg::this_grid().sync();             // all x1 written + visible

    // ---------- phase-2 prep (once per block, all L2-hot) ----------
    const int cg48 = tid % 48;
    const int slot = tid / 48;
    const int c0 = cg48 * 4;
    const char* x1b = (const char*)x1 + c0;

    const float DQ = 6.f / 255.f;
    float w2v[9][4];
#pragma unroll
    for (int k = 0; k < 9; ++k) {
        float4 w = *(const float4*)(W2 + k * 192 + c0);
        w2v[k][0] = w.x * DQ; w2v[k][1] = w.y * DQ; w2v[k][2] = w.z * DQ; w2v[k][3] = w.w * DQ;
    }
    float4 s2, bb2;
    {
        float4 gv = *(const float4*)(g2 + c0), bv = *(const float4*)(b2 + c0);
        float4 mv = *(const float4*)(m2 + c0), vv = *(const float4*)(v2 + c0);
        s2.x = gv.x * rsqrtf(vv.x + EPS); bb2.x = bv.x - mv.x * s2.x;
        s2.y = gv.y * rsqrtf(vv.y + EPS); bb2.y = bv.y - mv.y * s2.y;
        s2.z = gv.z * rsqrtf(vv.z + EPS); bb2.z = bv.z - mv.z * s2.z;
        s2.w = gv.w * rsqrtf(vv.w + EPS); bb2.w = bv.w - mv.w * s2.w;
    }
    BF8 bfrag[12];                          // B-frag: W3^T[outc=16t+m][h=32s+q*8+j]
#pragma unroll
    for (int s = 0; s < 6; ++s)
#pragma unroll
        for (int t = 0; t < 2; ++t)
#pragma unroll
            for (int j = 0; j < 8; ++j)
                bfrag[s * 2 + t].u[j] = f32_to_bf16(W3[(32 * s + q * 8 + j) * 32 + 16 * t + m]);
    float s3v[2], bb3v[2];
#pragma unroll
    for (int t = 0; t < 2; ++t) {
        int c = 16 * t + m;
        float w = g3[c] * rsqrtf(v3[c] + EPS);
        s3v[t] = w; bb3v[t] = b3[c] - m3[c] * w;
    }

    // ---------- phase 2: grid-stride over 48-row tiles (proven k2 body) ----------
    for (int tb = blockIdx.x; tb < nt2; tb += gridDim.x) {
        const int rowbase = tb * 48;
        for (int i = tid; i < 432; i += 192) {
            int r = i / 9, k = i - r * 9;
            int n = rowbase + r;
            int idx = (n < N) ? nbr[(size_t)n * 9 + k] : -1;
            offL[r * 12 + k] = (idx < 0) ? -1 : idx * 192;
        }
        __syncthreads();

#pragma unroll
        for (int it = 0; it < 6; ++it) {
            int r0 = it * 8 + slot, r1 = r0 + 4;
            const int* nA = &offL[r0 * 12];
            const int* nB = &offL[r1 * 12];
            int4 a03 = *(const int4*)nA; int4 a47 = *(const int4*)(nA + 4); int a8 = nA[8];
            int4 b03 = *(const int4*)nB; int4 b47 = *(const int4*)(nB + 4); int b8 = nB[8];
            int offA[9] = {a03.x, a03.y, a03.z, a03.w, a47.x, a47.y, a47.z, a47.w, a8};
            int offB[9] = {b03.x, b03.y, b03.z, b03.w, b47.x, b47.y, b47.z, b47.w, b8};
            unsigned gA[9], gB[9];
#pragma unroll
            for (int k = 0; k < 9; ++k) {
                gA[k] = *(const unsigned*)(x1b + (offA[k] < 0 ? 0 : offA[k]));
                gB[k] = *(const unsigned*)(x1b + (offB[k] < 0 ? 0 : offB[k]));
            }
            float a0 = 0.f, a1 = 0.f, a2 = 0.f, a3 = 0.f;
            float c0f = 0.f, c1 = 0.f, c2 = 0.f, c3 = 0.f;
#pragma unroll
            for (int k = 0; k < 9; ++k) {
                unsigned ga = offA[k] >= 0 ? gA[k] : 0u;
                unsigned gb = offB[k] >= 0 ? gB[k] : 0u;
                a0 = fmaf((float)(ga & 0xFF),         w2v[k][0], a0);
                a1 = fmaf((float)((ga >> 8) & 0xFF),  w2v[k][1], a1);
                a2 = fmaf((float)((ga >> 16) & 0xFF), w2v[k][2], a2);
                a3 = fmaf((float)(ga >> 24),          w2v[k][3], a3);
                c0f = fmaf((float)(gb & 0xFF),         w2v[k][0], c0f);
                c1  = fmaf((float)((gb >> 8) & 0xFF),  w2v[k][1], c1);
                c2  = fmaf((float)((gb >> 16) & 0xFF), w2v[k][2], c2);
                c3  = fmaf((float)(gb >> 24),          w2v[k][3], c3);
            }
            a0 = relu6f(fmaf(a0, s2.x, bb2.x));
            a1 = relu6f(fmaf(a1, s2.y, bb2.y));
            a2 = relu6f(fmaf(a2, s2.z, bb2.z));
            a3 = relu6f(fmaf(a3, s2.w, bb2.w));
            c0f = relu6f(fmaf(c0f, s2.x, bb2.x));
            c1  = relu6f(fmaf(c1,  s2.y, bb2.y));
            c2  = relu6f(fmaf(c2,  s2.z, bb2.z));
            c3  = relu6f(fmaf(c3,  s2.w, bb2.w));
            uint2 pA, pB;
            pA.x = (unsigned)f32_to_bf16(a0) | ((unsigned)f32_to_bf16(a1) << 16);
            pA.y = (unsigned)f32_to_bf16(a2) | ((unsigned)f32_to_bf16(a3) << 16);
            pB.x = (unsigned)f32_to_bf16(c0f) | ((unsigned)f32_to_bf16(c1) << 16);
            pB.y = (unsigned)f32_to_bf16(c2)  | ((unsigned)f32_to_bf16(c3) << 16);
            *(uint2*)(&x2L[r0 * 200 + c0]) = pA;
            *(uint2*)(&x2L[r1 * 200 + c0]) = pB;
        }
        __syncthreads();

        f32x4 acc0 = {0.f, 0.f, 0.f, 0.f}, acc1 = {0.f, 0.f, 0.f, 0.f};
        const int rw = wave * 16;
#pragma unroll
        for (int s = 0; s < 6; ++s) {
            bf16x8 a = *reinterpret_cast<const bf16x8*>(&x2L[(rw + m) * 200 + 32 * s + q * 8]);
            acc0 = __builtin_amdgcn_mfma_f32_16x16x32_bf16(a, bfrag[s * 2 + 0].v, acc0, 0, 0, 0);
            acc1 = __builtin_amdgcn_mfma_f32_16x16x32_bf16(a, bfrag[s * 2 + 1].v, acc1, 0, 0, 0);
        }

#pragma unroll
        for (int t = 0; t < 2; ++t) {
            f32x4 acc = (t == 0) ? acc0 : acc1;
            int c = 16 * t + m;
#pragma unroll
            for (int i = 0; i < 4; ++i) {
                int r = rowbase + rw + q * 4 + i;
                if (r < N) {
                    int o = r * 32 + c;
                    out[o] = fmaf(acc[i], s3v[t], bb3v[t]) + feats[o];
                }
            }
        }
        // next iter's offL write is disjoint from x2L; its gather writes are
        // fenced by the barrier after the offL fill -> 2 barriers/iter suffice.
    }
}

extern "C" void kernel_launch(void* const* d_in, const int* in_sizes, int n_in,
                              void* d_out, int out_size, void* d_ws, size_t ws_size,
                              hipStream_t stream) {
    const float* feats = (const float*)d_in[0];
    const int*   nbr   = (const int*)d_in[1];
    const float* W1    = (const float*)d_in[2];
    const float* W2    = (const float*)d_in[3];
    const float* W3    = (const float*)d_in[4];
    const float* g1 = (const float*)d_in[5];
    const float* b1 = (const float*)d_in[6];
    const float* m1 = (const float*)d_in[7];
    const float* v1 = (const float*)d_in[8];
    const float* g2 = (const float*)d_in[9];
    const float* b2 = (const float*)d_in[10];
    const float* m2 = (const float*)d_in[11];
    const float* v2 = (const float*)d_in[12];
    const float* g3 = (const float*)d_in[13];
    const float* b3 = (const float*)d_in[14];
    const float* m3 = (const float*)d_in[15];
    const float* v3 = (const float*)d_in[16];
    float* out = (float*)d_out;

    const int N = in_sizes[0] / 32;
    int nt1 = (N + 95) / 96;
    int nt2 = (N + 47) / 48;

    unsigned char* x1 = (unsigned char*)d_ws;   // only workspace use: N*192 u8

    // co-resident grid size: occupancy API x CU count (cached)
    static int s_grid = -1;
    if (s_grid < 0) {
        int dev = 0; hipGetDevice(&dev);
        int cus = 256;
        hipDeviceGetAttribute(&cus, hipDeviceAttributeMultiprocessorCount, dev);
        int occ = 0;
        hipOccupancyMaxActiveBlocksPerMultiprocessor(&occ, fused, 192, 0);
        if (occ < 1) occ = 1;
        s_grid = occ * cus;
    }
    int maxt = (nt1 > nt2) ? nt1 : nt2;
    int grid = (s_grid < maxt) ? s_grid : maxt;

    void* args[] = {
        (void*)&feats, (void*)&nbr, (void*)&W1, (void*)&W2, (void*)&W3,
        (void*)&g1, (void*)&b1, (void*)&m1, (void*)&v1,
        (void*)&g2, (void*)&b2, (void*)&m2, (void*)&v2,
        (void*)&g3, (void*)&b3, (void*)&m3, (void*)&v3,
        (void*)&x1, (void*)&out, (void*)&N, (void*)&nt1, (void*)&nt2
    };
    hipLaunchCooperativeKernel(fused, dim3(grid), dim3(192), args, 0u, stream);
}

// Round 3
// 204.708 us; speedup vs baseline: 1.5981x; 1.5981x over previous
//
#include <hip/hip_runtime.h>

#define EPS 1e-5f

typedef __bf16 bf16x8 __attribute__((ext_vector_type(8)));
typedef float f32x4 __attribute__((ext_vector_type(4)));

union BF8 { bf16x8 v; unsigned short u[8]; uint4 q; };

__device__ inline unsigned short f32_to_bf16(float f) {
    unsigned u = __builtin_bit_cast(unsigned, f);
    return (unsigned short)((u + 0x7FFFu + ((u >> 16) & 1u)) >> 16);
}
__device__ inline float relu6f(float x) { return fminf(fmaxf(x, 0.f), 6.f); }

// ---------------- K1: x1 = uint8-quant(relu6(bn1(feats @ W1))), MFMA ----------------
// 128 rows/block, 256 threads, LDS-FREE (only 1.5 KB bn1 constants).
// Operand-swapped MFMA: acc = mfma(W1^T-frag, feat-frag) -> lane owns 4 CONSECUTIVE
// channels (16t+4q+i) of ONE point -> pack 4 sat-u8 in a register, store dword
// STRAIGHT to global x1 (no LDS staging, no barrier, no readout pass).
// Every 64B line of x1 is fully covered by temporally-adjacent stores -> write
// traffic stays 38.4 MB. W1 frags + bn1 folded per-block (k0 eliminated).
__global__ __launch_bounds__(256) void k1_expand(
    const float* __restrict__ feats, const float* __restrict__ W1,
    const float* __restrict__ g1, const float* __restrict__ b1,
    const float* __restrict__ m1, const float* __restrict__ v1,
    unsigned char* __restrict__ x1, int N)
{
    __shared__ __align__(16) float bn1[384];
    const int tid = threadIdx.x;
    const int rowbase = blockIdx.x * 128;
    const int lane = tid & 63, wave = tid >> 6;
    const int m = lane & 15, q = lane >> 4;

    if (tid < 192) {                       // bn1 scale/bias (Q-folded), once per block
        const float Q = 255.f / 6.f;
        float s = g1[tid] * rsqrtf(v1[tid] + EPS);
        bn1[tid]       = s * Q;
        bn1[192 + tid] = (b1[tid] - m1[tid] * s) * Q;
    }

    // A-frag: W1^T[outch=16t+m][k=q*8+j], built from L2-hot W1 (same cvt as old k0)
    BF8 bf[12];
#pragma unroll
    for (int t = 0; t < 12; ++t)
#pragma unroll
        for (int j = 0; j < 8; ++j)
            bf[t].u[j] = f32_to_bf16(W1[(q * 8 + j) * 192 + 16 * t + m]);
    __syncthreads();

    // two 16-row tiles per wave
#pragma unroll
    for (int p = 0; p < 2; ++p) {
        const int tile = wave * 2 + p;              // 0..7
        const int row = rowbase + tile * 16 + m;
        float4 f0 = {0.f,0.f,0.f,0.f}, f1 = {0.f,0.f,0.f,0.f};
        if (row < N) {
            f0 = *(const float4*)(feats + (size_t)row * 32 + q * 8);
            f1 = *(const float4*)(feats + (size_t)row * 32 + q * 8 + 4);
        }
        BF8 af;                                     // B-frag: B[k=q*8+j][pt=m]
        af.u[0] = f32_to_bf16(f0.x); af.u[1] = f32_to_bf16(f0.y);
        af.u[2] = f32_to_bf16(f0.z); af.u[3] = f32_to_bf16(f0.w);
        af.u[4] = f32_to_bf16(f1.x); af.u[5] = f32_to_bf16(f1.y);
        af.u[6] = f32_to_bf16(f1.z); af.u[7] = f32_to_bf16(f1.w);

        f32x4 acc[12];
#pragma unroll
        for (int t = 0; t < 12; ++t) {
            f32x4 z = {0.f, 0.f, 0.f, 0.f};
            acc[t] = __builtin_amdgcn_mfma_f32_16x16x32_bf16(bf[t].v, af.v, z, 0, 0, 0);
        }

        if (row < N) {
            unsigned char* xr = x1 + (size_t)row * 192 + 4 * q;
#pragma unroll
            for (int t = 0; t < 12; ++t) {
                float4 sv = *(const float4*)(bn1 + 16 * t + 4 * q);        // LDS bcast
                float4 bv = *(const float4*)(bn1 + 192 + 16 * t + 4 * q);
                float y0 = fminf(fmaxf(fmaf(acc[t][0], sv.x, bv.x), 0.f), 255.f);
                float y1 = fminf(fmaxf(fmaf(acc[t][1], sv.y, bv.y), 0.f), 255.f);
                float y2 = fminf(fmaxf(fmaf(acc[t][2], sv.z, bv.z), 0.f), 255.f);
                float y3 = fminf(fmaxf(fmaf(acc[t][3], sv.w, bv.w), 0.f), 255.f);
                unsigned d = (unsigned)(y0 + 0.5f)
                           | ((unsigned)(y1 + 0.5f) << 8)
                           | ((unsigned)(y2 + 0.5f) << 16)
                           | ((unsigned)(y3 + 0.5f) << 24);
                *(unsigned*)(xr + 16 * t) = d;       // direct global dword store
            }
        }
    }
}

// ------- K2: fused depthwise gather (u8) + bn2 + relu6 + project GEMM + bn3 + residual -------
// Proven body (at ~3.2 TB/s random-gather fabric ceiling). Constants folded per-block
// from global at the SAME program points the table loads used to sit (preserves the
// VGPR=60-class live ranges: w2v/s2 before gather loop, bfrag/s3 after it).
__global__ __launch_bounds__(192) void k2_fused(
    const unsigned char* __restrict__ x1, const int* __restrict__ nbr,
    const float* __restrict__ W2, const float* __restrict__ W3,
    const float* __restrict__ g2, const float* __restrict__ b2,
    const float* __restrict__ m2, const float* __restrict__ v2,
    const float* __restrict__ g3, const float* __restrict__ b3,
    const float* __restrict__ m3, const float* __restrict__ v3,
    const float* __restrict__ feats, float* __restrict__ out, int N)
{
    __shared__ __align__(16) unsigned short x2L[48 * 200];
    __shared__ __align__(16) int offL[48 * 12];
    const int tid = threadIdx.x;
    const int rowbase = blockIdx.x * 48;

    for (int i = tid; i < 432; i += 192) {
        int r = i / 9, k = i - r * 9;
        int n = rowbase + r;
        int idx = (n < N) ? nbr[(size_t)n * 9 + k] : -1;
        offL[r * 12 + k] = (idx < 0) ? -1 : idx * 192;
    }

    const int cg = tid % 48;
    const int slot = tid / 48;
    const int c0 = cg * 4;
    const char* x1b = (const char*)x1 + c0;

    const float DQ = 6.f / 255.f;
    float w2v[9][4];
#pragma unroll
    for (int k = 0; k < 9; ++k) {
        float4 w = *(const float4*)(W2 + k * 192 + c0);
        w2v[k][0] = w.x * DQ; w2v[k][1] = w.y * DQ; w2v[k][2] = w.z * DQ; w2v[k][3] = w.w * DQ;
    }
    float4 s2, bb2;
    {
        float4 gv = *(const float4*)(g2 + c0), bv = *(const float4*)(b2 + c0);
        float4 mv = *(const float4*)(m2 + c0), vv = *(const float4*)(v2 + c0);
        s2.x = gv.x * rsqrtf(vv.x + EPS); bb2.x = bv.x - mv.x * s2.x;
        s2.y = gv.y * rsqrtf(vv.y + EPS); bb2.y = bv.y - mv.y * s2.y;
        s2.z = gv.z * rsqrtf(vv.z + EPS); bb2.z = bv.z - mv.z * s2.z;
        s2.w = gv.w * rsqrtf(vv.w + EPS); bb2.w = bv.w - mv.w * s2.w;
    }
    __syncthreads();

#pragma unroll
    for (int it = 0; it < 6; ++it) {
        int r0 = it * 8 + slot, r1 = r0 + 4;
        const int* nA = &offL[r0 * 12];
        const int* nB = &offL[r1 * 12];
        int4 a03 = *(const int4*)nA; int4 a47 = *(const int4*)(nA + 4); int a8 = nA[8];
        int4 b03 = *(const int4*)nB; int4 b47 = *(const int4*)(nB + 4); int b8 = nB[8];
        int offA[9] = {a03.x, a03.y, a03.z, a03.w, a47.x, a47.y, a47.z, a47.w, a8};
        int offB[9] = {b03.x, b03.y, b03.z, b03.w, b47.x, b47.y, b47.z, b47.w, b8};
        unsigned gA[9], gB[9];
#pragma unroll
        for (int k = 0; k < 9; ++k) {
            gA[k] = *(const unsigned*)(x1b + (offA[k] < 0 ? 0 : offA[k]));
            gB[k] = *(const unsigned*)(x1b + (offB[k] < 0 ? 0 : offB[k]));
        }
        float a0 = 0.f, a1 = 0.f, a2 = 0.f, a3 = 0.f;
        float c0f = 0.f, c1 = 0.f, c2 = 0.f, c3 = 0.f;
#pragma unroll
        for (int k = 0; k < 9; ++k) {
            unsigned ga = offA[k] >= 0 ? gA[k] : 0u;
            unsigned gb = offB[k] >= 0 ? gB[k] : 0u;
            a0 = fmaf((float)(ga & 0xFF),         w2v[k][0], a0);
            a1 = fmaf((float)((ga >> 8) & 0xFF),  w2v[k][1], a1);
            a2 = fmaf((float)((ga >> 16) & 0xFF), w2v[k][2], a2);
            a3 = fmaf((float)(ga >> 24),          w2v[k][3], a3);
            c0f = fmaf((float)(gb & 0xFF),         w2v[k][0], c0f);
            c1  = fmaf((float)((gb >> 8) & 0xFF),  w2v[k][1], c1);
            c2  = fmaf((float)((gb >> 16) & 0xFF), w2v[k][2], c2);
            c3  = fmaf((float)(gb >> 24),          w2v[k][3], c3);
        }
        a0 = relu6f(fmaf(a0, s2.x, bb2.x));
        a1 = relu6f(fmaf(a1, s2.y, bb2.y));
        a2 = relu6f(fmaf(a2, s2.z, bb2.z));
        a3 = relu6f(fmaf(a3, s2.w, bb2.w));
        c0f = relu6f(fmaf(c0f, s2.x, bb2.x));
        c1  = relu6f(fmaf(c1,  s2.y, bb2.y));
        c2  = relu6f(fmaf(c2,  s2.z, bb2.z));
        c3  = relu6f(fmaf(c3,  s2.w, bb2.w));
        uint2 pA, pB;
        pA.x = (unsigned)f32_to_bf16(a0) | ((unsigned)f32_to_bf16(a1) << 16);
        pA.y = (unsigned)f32_to_bf16(a2) | ((unsigned)f32_to_bf16(a3) << 16);
        pB.x = (unsigned)f32_to_bf16(c0f) | ((unsigned)f32_to_bf16(c1) << 16);
        pB.y = (unsigned)f32_to_bf16(c2)  | ((unsigned)f32_to_bf16(c3) << 16);
        *(uint2*)(&x2L[r0 * 200 + c0]) = pA;
        *(uint2*)(&x2L[r1 * 200 + c0]) = pB;
    }
    __syncthreads();

    const int lane = tid & 63;
    const int wave = tid >> 6;
    const int m = lane & 15;
    const int q = lane >> 4;

    // B-frag: W3^T[outc=16t+m][h=32s+q*8+j], built here (post-gather) from L2-hot W3
    BF8 bfrag[12];
#pragma unroll
    for (int s = 0; s < 6; ++s)
#pragma unroll
        for (int t = 0; t < 2; ++t)
#pragma unroll
            for (int j = 0; j < 8; ++j)
                bfrag[s * 2 + t].u[j] = f32_to_bf16(W3[(32 * s + q * 8 + j) * 32 + 16 * t + m]);

    f32x4 acc0 = {0.f, 0.f, 0.f, 0.f}, acc1 = {0.f, 0.f, 0.f, 0.f};
    const int rw = wave * 16;
#pragma unroll
    for (int s = 0; s < 6; ++s) {
        bf16x8 a = *reinterpret_cast<const bf16x8*>(&x2L[(rw + m) * 200 + 32 * s + q * 8]);
        acc0 = __builtin_amdgcn_mfma_f32_16x16x32_bf16(a, bfrag[s * 2 + 0].v, acc0, 0, 0, 0);
        acc1 = __builtin_amdgcn_mfma_f32_16x16x32_bf16(a, bfrag[s * 2 + 1].v, acc1, 0, 0, 0);
    }

#pragma unroll
    for (int t = 0; t < 2; ++t) {
        f32x4 acc = (t == 0) ? acc0 : acc1;
        int c = 16 * t + m;
        float w = g3[c] * rsqrtf(v3[c] + EPS);
        float s3 = w, bb3 = b3[c] - m3[c] * w;
#pragma unroll
        for (int i = 0; i < 4; ++i) {
            int r = rowbase + rw + q * 4 + i;
            if (r < N) {
                int o = r * 32 + c;
                out[o] = fmaf(acc[i], s3, bb3) + feats[o];
            }
        }
    }
}

extern "C" void kernel_launch(void* const* d_in, const int* in_sizes, int n_in,
                              void* d_out, int out_size, void* d_ws, size_t ws_size,
                              hipStream_t stream) {
    const float* feats = (const float*)d_in[0];
    const int*   nbr   = (const int*)d_in[1];
    const float* W1    = (const float*)d_in[2];
    const float* W2    = (const float*)d_in[3];
    const float* W3    = (const float*)d_in[4];
    const float* g1 = (const float*)d_in[5];
    const float* b1 = (const float*)d_in[6];
    const float* m1 = (const float*)d_in[7];
    const float* v1 = (const float*)d_in[8];
    const float* g2 = (const float*)d_in[9];
    const float* b2 = (const float*)d_in[10];
    const float* m2 = (const float*)d_in[11];
    const float* v2 = (const float*)d_in[12];
    const float* g3 = (const float*)d_in[13];
    const float* b3 = (const float*)d_in[14];
    const float* m3 = (const float*)d_in[15];
    const float* v3 = (const float*)d_in[16];
    float* out = (float*)d_out;

    const int N = in_sizes[0] / 32;

    unsigned char* x1 = (unsigned char*)d_ws;   // only workspace use: N*192 u8

    k1_expand<<<dim3((N + 127) / 128), dim3(256), 0, stream>>>(
        feats, W1, g1, b1, m1, v1, x1, N);
    k2_fused<<<dim3((N + 47) / 48), dim3(192), 0, stream>>>(
        x1, nbr, W2, W3, g2, b2, m2, v2, g3, b3, m3, v3, feats, out, N);
}